// Round 9
// baseline (105.509 us; speedup 1.0000x reference)
//
#include <hip/hip_runtime.h>
#include <hip/hip_bf16.h>
#include <cstdint>

#define DEVFN __device__ __forceinline__

namespace {

constexpr int B = 16, T = 8192, C = 128, H = 128, K = 5;
constexpr int TP1 = T + 1;                      // 8193 slots (slot 0 = init row)
constexpr int N = B * TP1 * H;                  // 16,779,264
constexpr int NKK = 20;                         // (C*K)/32 K-steps
constexpr int NCH = T / 64;                     // 128 chunks over slots [1+64j, 64+64j]
constexpr int NSER = B * H;                     // 2048 scan series
constexpr int WF_ELE = NKK * 8 * 64 * 2 * 8;    // bf16 fragment elems (F+Z interleaved)
constexpr int XPITCH = 136;                     // LDS row pitch in shorts (272 B = 17*16B)

typedef __attribute__((ext_vector_type(8))) short short8;
typedef __attribute__((ext_vector_type(4))) float f32x4;

DEVFN float sigmoidf(float x) { return 1.0f / (1.0f + __expf(-x)); }
DEVFN unsigned bfb(float v) {
  __hip_bfloat16 h = __float2bfloat16(v);
  return (unsigned)*reinterpret_cast<unsigned short*>(&h);
}

// Segment-summary compose: L=[..b] then R=[b+1..]:
//   P* = P*_L * Fl_L * P*_R ; Q = Fl_L * P*_R * Q_L + Q_R ; Fl = Fl_R
DEVFN void compose(float& P, float& Q, float& Fl, float Pr, float Qr, float Flr) {
  float t = Fl * Pr;
  P = P * t;
  Q = fmaf(t, Q, Qr);
  Fl = Flr;
}

// ---------------------------------------------------------------------------
// Weights (H,C,K) f32 -> MFMA B-fragment layout bf16 (16x16x32), F/Z interleaved:
//   idx = (((kk*8 + nf8)*64 + lane)*2 + fz)*8 + j
//   value = Bmat[kdim = kk*32 + (lane>>4)*8 + j][h = nf8*16 + (lane&15)]
__global__ __launch_bounds__(256)
void wprep_kernel(const float* __restrict__ fw, const float* __restrict__ zw,
                  short* __restrict__ Wfrag) {
  int idx = blockIdx.x * 256 + threadIdx.x;
  if (idx >= WF_ELE) return;
  int j = idx & 7;
  int fz = (idx >> 3) & 1;
  int lane = (idx >> 4) & 63;
  int nf8 = (idx >> 10) & 7;
  int kk = idx >> 13;
  int kdim = kk * 32 + ((lane >> 4) << 3) + j;
  int h = nf8 * 16 + (lane & 15);
  int k = kdim >> 7, c = kdim & 127;
  int src = (h * C + c) * K + k;
  float w = fz ? zw[src] : fw[src];
  Wfrag[idx] = (short)bfb(w);
}

// ---------------------------------------------------------------------------
// Conv via MFMA + in-epilogue chunk summaries (round-6 best, verbatim).
__global__ __launch_bounds__(512, 4)
void conv_mfma_kernel(const float* __restrict__ x,
                      const float* __restrict__ fb, const float* __restrict__ zb,
                      const short* __restrict__ Wfrag,
                      unsigned* __restrict__ FG,
                      float* __restrict__ sumP, float* __restrict__ sumQ) {
  __shared__ short xs[68 * XPITCH];  // rows r <-> t = t0-2+r; 272B pitch
  const int b = blockIdx.y;
  const int t0 = blockIdx.x * 64;
  const int tid = threadIdx.x;
  const int lane = tid & 63;
  const int wid = tid >> 6;          // 0..7 = h-col group
  const int lrow = lane & 15;
  const int lg = lane >> 4;

  // ---- stage x tile as bf16 (68 rows x 128 c), linear padded layout ----
  for (int i = tid; i < 68 * 16; i += 512) {
    int r = i >> 4, co = (i & 15) << 3;
    int t = t0 - 2 + r;
    f32x4 v0 = {0.f, 0.f, 0.f, 0.f}, v1 = v0;
    if (t >= 0 && t < T) {
      const f32x4* p = reinterpret_cast<const f32x4*>(x + ((size_t)(b * T + t)) * C + co);
      v0 = p[0]; v1 = p[1];
    }
    short8 s;
    s[0] = (short)bfb(v0[0]); s[1] = (short)bfb(v0[1]); s[2] = (short)bfb(v0[2]); s[3] = (short)bfb(v0[3]);
    s[4] = (short)bfb(v1[0]); s[5] = (short)bfb(v1[1]); s[6] = (short)bfb(v1[2]); s[7] = (short)bfb(v1[3]);
    *reinterpret_cast<short8*>(xs + r * XPITCH + co) = s;
  }
  __syncthreads();

  f32x4 accF[4], accZ[4];
#pragma unroll
  for (int mf = 0; mf < 4; ++mf) { accF[mf] = {0.f,0.f,0.f,0.f}; accZ[mf] = {0.f,0.f,0.f,0.f}; }

  const char* xsb = reinterpret_cast<const char*>(xs);
  const short8* wb = reinterpret_cast<const short8*>(Wfrag) + (wid * 128 + lane * 2);
  const int abase = lrow * 272 + lg * 16;

  // ---- software-pipelined K-loop (sched_barrier-pinned) ----
  short8 wf[4], wz[4], av[2][4];
#pragma unroll
  for (int p = 0; p < 3; ++p) {            // weights for kk=0,1,2
    wf[p] = wb[p * 1024];
    wz[p] = wb[p * 1024 + 1];
  }
#pragma unroll
  for (int mf = 0; mf < 4; ++mf)           // a-frags for kk=0 (k=0, cq=0)
    av[0][mf] = *reinterpret_cast<const short8*>(xsb + (abase + (mf * 16) * 272));

#pragma unroll
  for (int kk = 0; kk < NKK; ++kk) {
    __builtin_amdgcn_sched_barrier(0);     // fence: loads below stay below MFMAs above
    if (kk + 3 < NKK) {                    // weight prefetch, 3 iters ahead
      const int o = (kk + 3) * 1024;
      wf[(kk + 3) & 3] = wb[o];
      wz[(kk + 3) & 3] = wb[o + 1];
    }
    if (kk + 1 < NKK) {                    // a-frag prefetch, 1 iter ahead
      const int k1 = (kk + 1) >> 2;        // compile-time
      const int cq1 = ((kk + 1) & 3) << 6; // compile-time
#pragma unroll
      for (int mf = 0; mf < 4; ++mf)
        av[(kk + 1) & 1][mf] =
            *reinterpret_cast<const short8*>(xsb + (abase + (mf * 16 + k1) * 272 + cq1));
    }
    __builtin_amdgcn_sched_barrier(0);     // fence: loads cannot sink past MFMAs below
#pragma unroll
    for (int mf = 0; mf < 4; ++mf) {
      accF[mf] = __builtin_amdgcn_mfma_f32_16x16x32_bf16(av[kk & 1][mf], wf[kk & 3], accF[mf], 0, 0, 0);
      accZ[mf] = __builtin_amdgcn_mfma_f32_16x16x32_bf16(av[kk & 1][mf], wz[kk & 3], accZ[mf], 0, 0, 0);
    }
  }

  // ---- epilogue: FG stores + chunk summary (incremental, no arrays) ----
  const int cblk = blockIdx.x;
  const int h = wid * 16 + lrow;
  const float biasF = fb[h], biasZ = zb[h];
  float cP = 1.f, cQ = 0.f, cFl = 1.f;
#pragma unroll
  for (int mf = 0; mf < 4; ++mf) {
    float y = 0.f, P = 1.f, prevF = 1.f;
#pragma unroll
    for (int j = 0; j < 4; ++j) {
      int m = mf * 16 + lg * 4 + j;
      int s = t0 + m + 1;                       // gate-slot index
      float rf = accF[mf][j] + biasF;
      float rz = accZ[mf][j] + biasZ;
      float F = sigmoidf(rf);
      float G = sigmoidf(rz) * (1.0f - F);
      FG[(size_t)(b * TP1 + s) * H + h] = bfb(F) | (bfb(G) << 16);
      if (j == 0) { y = G; P = 1.f; }
      else { P *= prevF; y = fmaf(prevF, y, G); }
      prevF = F;
    }
    // compose across lg (4 groups of 4 rows) — 2-level tree, valid on lg==0
    float tP = P, tQ = y, tFl = prevF;
    {
      float pP = __shfl(tP, lane + 16, 64);
      float pQ = __shfl(tQ, lane + 16, 64);
      float pF = __shfl(tFl, lane + 16, 64);
      compose(tP, tQ, tFl, pP, pQ, pF);
      pP = __shfl(tP, lane + 32, 64);
      pQ = __shfl(tQ, lane + 32, 64);
      pF = __shfl(tFl, lane + 32, 64);
      compose(tP, tQ, tFl, pP, pQ, pF);
    }
    if (mf == 0) { cP = tP; cQ = tQ; cFl = tFl; }
    else compose(cP, cQ, cFl, tP, tQ, tFl);
  }
  if (lg == 0) {
    int sidx = cblk * NSER + b * H + h;
    sumP[sidx] = cP;
    sumQ[sidx] = cQ;
  }
}

// ---------------------------------------------------------------------------
// scanB: init row (slot 0) + sequential chain over chunk summaries.
// Latency fix: batch 8 iterations' independent loads (sumP/sumQ/FG) into
// unrolled arrays BEFORE the serial compose chain -> 24 loads in flight,
// exposed latency / 8. cin aliases sumP (read-before-write, now group-wise:
// group's loads all precede group's stores, j-disjoint across groups).
__global__ void scanB_kernel(const float* __restrict__ init,
                             const unsigned* __restrict__ FG_r,
                             unsigned* __restrict__ FG_w,
                             const float* __restrict__ sumQ,
                             float* __restrict__ sumP_cin,   // in: P*, out: cin
                             float* __restrict__ out) {
  int g = blockIdx.x * blockDim.x + threadIdx.x;   // 0..NSER-1 = b*128+h
  int b = g >> 7, h = g & (H - 1);
  float rf = init[g];
  float rz = init[NSER + g];
  float F0 = sigmoidf(rf), z = sigmoidf(rz);
  float G0 = z * (1.0f - F0);
  size_t base = (size_t)b * TP1 * H + h;
  FG_w[base] = bfb(F0) | (bfb(G0) << 16);
  out[base] = G0;
  float y = G0;        // y[0]
  float Fp = F0;       // F[slot 64j] entering group
  for (int j0 = 0; j0 < NCH; j0 += 8) {
    float ps[8], qs[8], fl[8];
#pragma unroll
    for (int u = 0; u < 8; ++u) {
      int sidx = (j0 + u) * NSER + g;
      ps[u] = sumP_cin[sidx];
      qs[u] = sumQ[sidx];
      int jn = j0 + u + 1;
      fl[u] = (jn < NCH)
                  ? __uint_as_float(FG_r[base + (size_t)(64 * jn) * H] << 16)
                  : 1.0f;
    }
#pragma unroll
    for (int u = 0; u < 8; ++u) {
      sumP_cin[(j0 + u) * NSER + g] = y;        // cin for chunk j0+u
      y = fmaf(Fp * ps[u], y, qs[u]);           // y[64(j0+u+1)]
      Fp = fl[u];
    }
  }
}

// ---------------------------------------------------------------------------
// scanC: local rescan with carry-in, vectorized 4 series/thread.
// Block = 4 chunks x 128 h; thread (sub=tid>>5, hq=(tid&31)*4) owns chunk
// j = 4*blockIdx.x+sub, h-quad [hq,hq+4). uint4 FG loads / float4 out stores
// (16 B/lane, fully coalesced); unroll 8 keeps 8 loads in flight.
__global__ __launch_bounds__(128)
void scanC_kernel(const unsigned* __restrict__ FG, const float* __restrict__ cin,
                  float* __restrict__ out) {
  const int b = blockIdx.y;
  const int sub = threadIdx.x >> 5;
  const int j = blockIdx.x * 4 + sub;
  const int hq = (threadIdx.x & 31) * 4;
  const int s0 = 1 + j * 64;
  const size_t base = (size_t)b * TP1 * H + hq;

  const float4* pc = reinterpret_cast<const float4*>(cin + j * NSER + b * H + hq);
  float4 yv = *pc;
  float y0 = yv.x, y1 = yv.y, y2 = yv.z, y3 = yv.w;

  const uint4* p = reinterpret_cast<const uint4*>(FG + base + (size_t)s0 * H) - (H / 4);
  uint4 uf = *p;                                   // row 64j -> F carry
  p += (H / 4);
  float F0 = __uint_as_float(uf.x << 16), F1 = __uint_as_float(uf.y << 16);
  float F2 = __uint_as_float(uf.z << 16), F3 = __uint_as_float(uf.w << 16);

  float4* po = reinterpret_cast<float4*>(out + base + (size_t)s0 * H);
#pragma unroll 8
  for (int t = 0; t < 64; ++t) {
    uint4 u = *p; p += (H / 4);
    y0 = fmaf(F0, y0, __uint_as_float(u.x & 0xffff0000u));
    y1 = fmaf(F1, y1, __uint_as_float(u.y & 0xffff0000u));
    y2 = fmaf(F2, y2, __uint_as_float(u.z & 0xffff0000u));
    y3 = fmaf(F3, y3, __uint_as_float(u.w & 0xffff0000u));
    F0 = __uint_as_float(u.x << 16); F1 = __uint_as_float(u.y << 16);
    F2 = __uint_as_float(u.z << 16); F3 = __uint_as_float(u.w << 16);
    *po = make_float4(y0, y1, y2, y3); po += (H / 4);
  }
}

}  // namespace

// ---------------------------------------------------------------------------
extern "C" void kernel_launch(void* const* d_in, const int* in_sizes, int n_in,
                              void* d_out, int out_size, void* d_ws, size_t ws_size,
                              hipStream_t stream) {
  const float* x    = (const float*)d_in[0];
  const float* init = (const float*)d_in[1];
  const float* zw   = (const float*)d_in[2];
  const float* zb   = (const float*)d_in[3];
  const float* fw   = (const float*)d_in[4];
  const float* fb   = (const float*)d_in[5];
  float* out = (float*)d_out;
  char* ws = (char*)d_ws;

  // ws layout: [0,4N) FG; then sumP (1MB, becomes cin), sumQ (1MB), Wfrag (0.33MB).
  unsigned* FG = (unsigned*)ws;
  float* sumP = (float*)(ws + (size_t)N * 4);
  float* sumQ = sumP + (size_t)NCH * NSER;
  short* Wfrag = (short*)(sumQ + (size_t)NCH * NSER);

  wprep_kernel<<<(WF_ELE + 255) / 256, 256, 0, stream>>>(fw, zw, Wfrag);
  conv_mfma_kernel<<<dim3(NCH, B), 512, 0, stream>>>(x, fb, zb, Wfrag, FG, sumP, sumQ);
  scanB_kernel<<<16, 128, 0, stream>>>(init, FG, FG, sumQ, sumP, out);
  scanC_kernel<<<dim3(NCH / 4, B), 128, 0, stream>>>(FG, sumP, out);
}

// Round 10
// 99.596 us; speedup vs baseline: 1.0594x; 1.0594x over previous
//
#include <hip/hip_runtime.h>
#include <hip/hip_bf16.h>
#include <cstdint>

#define DEVFN __device__ __forceinline__

namespace {

constexpr int B = 16, T = 8192, C = 128, H = 128, K = 5;
constexpr int TP1 = T + 1;                      // 8193 slots (slot 0 = init row)
constexpr int N = B * TP1 * H;                  // 16,779,264
constexpr int NKK = 20;                         // (C*K)/32 K-steps
constexpr int NCH = T / 64;                     // 128 chunks over slots [1+64j, 64+64j]
constexpr int NSER = B * H;                     // 2048 scan series
constexpr int WF_ELE = NKK * 8 * 64 * 2 * 8;    // bf16 fragment elems (F+Z interleaved)
constexpr int XPITCH = 136;                     // LDS row pitch in shorts (272 B = 17*16B)

typedef __attribute__((ext_vector_type(8))) short short8;
typedef __attribute__((ext_vector_type(4))) float f32x4;

DEVFN float sigmoidf(float x) { return 1.0f / (1.0f + __expf(-x)); }
DEVFN unsigned bfb(float v) {
  __hip_bfloat16 h = __float2bfloat16(v);
  return (unsigned)*reinterpret_cast<unsigned short*>(&h);
}

// Segment-summary compose: L=[..b] then R=[b+1..]:
//   P* = P*_L * Fl_L * P*_R ; Q = Fl_L * P*_R * Q_L + Q_R ; Fl = Fl_R
DEVFN void compose(float& P, float& Q, float& Fl, float Pr, float Qr, float Flr) {
  float t = Fl * Pr;
  P = P * t;
  Q = fmaf(t, Q, Qr);
  Fl = Flr;
}

// ---------------------------------------------------------------------------
// Weights (H,C,K) f32 -> MFMA B-fragment layout bf16 (16x16x32), F/Z interleaved:
//   idx = (((kk*8 + nf8)*64 + lane)*2 + fz)*8 + j
//   value = Bmat[kdim = kk*32 + (lane>>4)*8 + j][h = nf8*16 + (lane&15)]
__global__ __launch_bounds__(256)
void wprep_kernel(const float* __restrict__ fw, const float* __restrict__ zw,
                  short* __restrict__ Wfrag) {
  int idx = blockIdx.x * 256 + threadIdx.x;
  if (idx >= WF_ELE) return;
  int j = idx & 7;
  int fz = (idx >> 3) & 1;
  int lane = (idx >> 4) & 63;
  int nf8 = (idx >> 10) & 7;
  int kk = idx >> 13;
  int kdim = kk * 32 + ((lane >> 4) << 3) + j;
  int h = nf8 * 16 + (lane & 15);
  int k = kdim >> 7, c = kdim & 127;
  int src = (h * C + c) * K + k;
  float w = fz ? zw[src] : fw[src];
  Wfrag[idx] = (short)bfb(w);
}

// ---------------------------------------------------------------------------
// Conv via MFMA + in-epilogue chunk summaries (round-6 best, verbatim).
// Structural plateau notes (r1-r9): LDS-read halving, weight-stream halving,
// occupancy 8w/SIMD, and grid fusion all measured as neutral-or-worse; the
// sched_barrier-pinned a-frag double buffer (+3 us) is the net winner.
__global__ __launch_bounds__(512, 4)
void conv_mfma_kernel(const float* __restrict__ x,
                      const float* __restrict__ fb, const float* __restrict__ zb,
                      const short* __restrict__ Wfrag,
                      unsigned* __restrict__ FG,
                      float* __restrict__ sumP, float* __restrict__ sumQ) {
  __shared__ short xs[68 * XPITCH];  // rows r <-> t = t0-2+r; 272B pitch
  const int b = blockIdx.y;
  const int t0 = blockIdx.x * 64;
  const int tid = threadIdx.x;
  const int lane = tid & 63;
  const int wid = tid >> 6;          // 0..7 = h-col group
  const int lrow = lane & 15;
  const int lg = lane >> 4;

  // ---- stage x tile as bf16 (68 rows x 128 c), linear padded layout ----
  for (int i = tid; i < 68 * 16; i += 512) {
    int r = i >> 4, co = (i & 15) << 3;
    int t = t0 - 2 + r;
    f32x4 v0 = {0.f, 0.f, 0.f, 0.f}, v1 = v0;
    if (t >= 0 && t < T) {
      const f32x4* p = reinterpret_cast<const f32x4*>(x + ((size_t)(b * T + t)) * C + co);
      v0 = p[0]; v1 = p[1];
    }
    short8 s;
    s[0] = (short)bfb(v0[0]); s[1] = (short)bfb(v0[1]); s[2] = (short)bfb(v0[2]); s[3] = (short)bfb(v0[3]);
    s[4] = (short)bfb(v1[0]); s[5] = (short)bfb(v1[1]); s[6] = (short)bfb(v1[2]); s[7] = (short)bfb(v1[3]);
    *reinterpret_cast<short8*>(xs + r * XPITCH + co) = s;
  }
  __syncthreads();

  f32x4 accF[4], accZ[4];
#pragma unroll
  for (int mf = 0; mf < 4; ++mf) { accF[mf] = {0.f,0.f,0.f,0.f}; accZ[mf] = {0.f,0.f,0.f,0.f}; }

  const char* xsb = reinterpret_cast<const char*>(xs);
  const short8* wb = reinterpret_cast<const short8*>(Wfrag) + (wid * 128 + lane * 2);
  const int abase = lrow * 272 + lg * 16;

  // ---- software-pipelined K-loop (sched_barrier-pinned) ----
  short8 wf[4], wz[4], av[2][4];
#pragma unroll
  for (int p = 0; p < 3; ++p) {            // weights for kk=0,1,2
    wf[p] = wb[p * 1024];
    wz[p] = wb[p * 1024 + 1];
  }
#pragma unroll
  for (int mf = 0; mf < 4; ++mf)           // a-frags for kk=0 (k=0, cq=0)
    av[0][mf] = *reinterpret_cast<const short8*>(xsb + (abase + (mf * 16) * 272));

#pragma unroll
  for (int kk = 0; kk < NKK; ++kk) {
    __builtin_amdgcn_sched_barrier(0);     // fence: loads below stay below MFMAs above
    if (kk + 3 < NKK) {                    // weight prefetch, 3 iters ahead
      const int o = (kk + 3) * 1024;
      wf[(kk + 3) & 3] = wb[o];
      wz[(kk + 3) & 3] = wb[o + 1];
    }
    if (kk + 1 < NKK) {                    // a-frag prefetch, 1 iter ahead
      const int k1 = (kk + 1) >> 2;        // compile-time
      const int cq1 = ((kk + 1) & 3) << 6; // compile-time
#pragma unroll
      for (int mf = 0; mf < 4; ++mf)
        av[(kk + 1) & 1][mf] =
            *reinterpret_cast<const short8*>(xsb + (abase + (mf * 16 + k1) * 272 + cq1));
    }
    __builtin_amdgcn_sched_barrier(0);     // fence: loads cannot sink past MFMAs below
#pragma unroll
    for (int mf = 0; mf < 4; ++mf) {
      accF[mf] = __builtin_amdgcn_mfma_f32_16x16x32_bf16(av[kk & 1][mf], wf[kk & 3], accF[mf], 0, 0, 0);
      accZ[mf] = __builtin_amdgcn_mfma_f32_16x16x32_bf16(av[kk & 1][mf], wz[kk & 3], accZ[mf], 0, 0, 0);
    }
  }

  // ---- epilogue: FG stores + chunk summary (incremental, no arrays) ----
  const int cblk = blockIdx.x;
  const int h = wid * 16 + lrow;
  const float biasF = fb[h], biasZ = zb[h];
  float cP = 1.f, cQ = 0.f, cFl = 1.f;
#pragma unroll
  for (int mf = 0; mf < 4; ++mf) {
    float y = 0.f, P = 1.f, prevF = 1.f;
#pragma unroll
    for (int j = 0; j < 4; ++j) {
      int m = mf * 16 + lg * 4 + j;
      int s = t0 + m + 1;                       // gate-slot index
      float rf = accF[mf][j] + biasF;
      float rz = accZ[mf][j] + biasZ;
      float F = sigmoidf(rf);
      float G = sigmoidf(rz) * (1.0f - F);
      FG[(size_t)(b * TP1 + s) * H + h] = bfb(F) | (bfb(G) << 16);
      if (j == 0) { y = G; P = 1.f; }
      else { P *= prevF; y = fmaf(prevF, y, G); }
      prevF = F;
    }
    // compose across lg (4 groups of 4 rows) — 2-level tree, valid on lg==0
    float tP = P, tQ = y, tFl = prevF;
    {
      float pP = __shfl(tP, lane + 16, 64);
      float pQ = __shfl(tQ, lane + 16, 64);
      float pF = __shfl(tFl, lane + 16, 64);
      compose(tP, tQ, tFl, pP, pQ, pF);
      pP = __shfl(tP, lane + 32, 64);
      pQ = __shfl(tQ, lane + 32, 64);
      pF = __shfl(tFl, lane + 32, 64);
      compose(tP, tQ, tFl, pP, pQ, pF);
    }
    if (mf == 0) { cP = tP; cQ = tQ; cFl = tFl; }
    else compose(cP, cQ, cFl, tP, tQ, tFl);
  }
  if (lg == 0) {
    int sidx = cblk * NSER + b * H + h;
    sumP[sidx] = cP;
    sumQ[sidx] = cQ;
  }
}

// ---------------------------------------------------------------------------
// scanB: init row (slot 0) + sequential chain over chunk summaries.
// Only 2048 threads exist (no TLP to hide latency) -> batch 8 iterations'
// independent loads ahead of the serial compose chain: 24 loads in flight,
// exposed chain latency / 8. cin aliases sumP (read-before-write, group-wise
// safe: each thread touches only its own series column).
__global__ void scanB_kernel(const float* __restrict__ init,
                             const unsigned* __restrict__ FG_r,
                             unsigned* __restrict__ FG_w,
                             const float* __restrict__ sumQ,
                             float* __restrict__ sumP_cin,   // in: P*, out: cin
                             float* __restrict__ out) {
  int g = blockIdx.x * blockDim.x + threadIdx.x;   // 0..NSER-1 = b*128+h
  int b = g >> 7, h = g & (H - 1);
  float rf = init[g];
  float rz = init[NSER + g];
  float F0 = sigmoidf(rf), z = sigmoidf(rz);
  float G0 = z * (1.0f - F0);
  size_t base = (size_t)b * TP1 * H + h;
  FG_w[base] = bfb(F0) | (bfb(G0) << 16);
  out[base] = G0;
  float y = G0;        // y[0]
  float Fp = F0;       // F[slot 64j] entering group
  for (int j0 = 0; j0 < NCH; j0 += 8) {
    float ps[8], qs[8], fl[8];
#pragma unroll
    for (int u = 0; u < 8; ++u) {
      int sidx = (j0 + u) * NSER + g;
      ps[u] = sumP_cin[sidx];
      qs[u] = sumQ[sidx];
      int jn = j0 + u + 1;
      fl[u] = (jn < NCH)
                  ? __uint_as_float(FG_r[base + (size_t)(64 * jn) * H] << 16)
                  : 1.0f;
    }
#pragma unroll
    for (int u = 0; u < 8; ++u) {
      sumP_cin[(j0 + u) * NSER + g] = y;        // cin for chunk j0+u
      y = fmaf(Fp * ps[u], y, qs[u]);           // y[64(j0+u+1)]
      Fp = fl[u];
    }
  }
}

// ---------------------------------------------------------------------------
// scanC: chunk j covers slots [1+64j, 64+64j]; local rescan with carry-in.
// r6 form: one chunk per 128-thr block, 2048 blocks (16 waves/CU). r9 showed
// that trading this TLP for wider per-thread loads LOSES on this latency-
// bound loop -- keep max parallelism, scalar 4B loads.
__global__ __launch_bounds__(128)
void scanC_kernel(const unsigned* __restrict__ FG, const float* __restrict__ cin,
                  float* __restrict__ out) {
  const int b = blockIdx.y, j = blockIdx.x, h = threadIdx.x;
  const int s0 = 1 + j * 64;
  float y = cin[j * NSER + b * H + h];
  const size_t base = (size_t)b * TP1 * H + h;
  const unsigned* p = FG + base + (size_t)s0 * H;
  float Fprev = __uint_as_float(p[-H] << 16);     // F[64j]
  float* po = out + base + (size_t)s0 * H;
#pragma unroll 8
  for (int t = 0; t < 64; ++t) {
    unsigned u = *p; p += H;
    float G = __uint_as_float(u & 0xffff0000u);
    y = fmaf(Fprev, y, G);
    Fprev = __uint_as_float(u << 16);
    *po = y; po += H;
  }
}

}  // namespace

// ---------------------------------------------------------------------------
extern "C" void kernel_launch(void* const* d_in, const int* in_sizes, int n_in,
                              void* d_out, int out_size, void* d_ws, size_t ws_size,
                              hipStream_t stream) {
  const float* x    = (const float*)d_in[0];
  const float* init = (const float*)d_in[1];
  const float* zw   = (const float*)d_in[2];
  const float* zb   = (const float*)d_in[3];
  const float* fw   = (const float*)d_in[4];
  const float* fb   = (const float*)d_in[5];
  float* out = (float*)d_out;
  char* ws = (char*)d_ws;

  // ws layout: [0,4N) FG; then sumP (1MB, becomes cin), sumQ (1MB), Wfrag (0.33MB).
  unsigned* FG = (unsigned*)ws;
  float* sumP = (float*)(ws + (size_t)N * 4);
  float* sumQ = sumP + (size_t)NCH * NSER;
  short* Wfrag = (short*)(sumQ + (size_t)NCH * NSER);

  wprep_kernel<<<(WF_ELE + 255) / 256, 256, 0, stream>>>(fw, zw, Wfrag);
  conv_mfma_kernel<<<dim3(NCH, B), 512, 0, stream>>>(x, fb, zb, Wfrag, FG, sumP, sumQ);
  scanB_kernel<<<16, 128, 0, stream>>>(init, FG, FG, sumQ, sumP, out);
  scanC_kernel<<<dim3(NCH, B), 128, 0, stream>>>(FG, sumP, out);
}